// Round 3
// baseline (2710.005 us; speedup 1.0000x reference)
//
#include <hip/hip_runtime.h>
#include <hip/hip_bf16.h>

#define U_N 200000
#define I_N 100000
#define G_N 10000
#define B_N 8192
#define NHG (U_N + G_N)   /* 210000 */
#define GG_K 10000

static __device__ __forceinline__ float sigmoidf_(float x) {
    return 1.0f / (1.0f + __expf(-x));
}

static __device__ __forceinline__ float ldf(const float* p) { return *p; }
static __device__ __forceinline__ float ldf(const __hip_bfloat16* p) { return __bfloat162float(*p); }

// ---------------- CSR build (hg only) ----------------

__global__ void k_hist(const int* __restrict__ rows, int* __restrict__ cnt, int nE, int maxRow) {
    int e = blockIdx.x * 256 + threadIdx.x;
    if (e >= nE) return;
    int r = rows[e];
    if (r < maxRow) atomicAdd(&cnt[r], 1);
}

__global__ void k_scan_partial(const int* __restrict__ in, int* __restrict__ out,
                               int* __restrict__ bsums, int n) {
    __shared__ int sh[256];
    int tid = threadIdx.x;
    int base = blockIdx.x * 1024 + tid * 4;
    int v0 = (base + 0 < n) ? in[base + 0] : 0;
    int v1 = (base + 1 < n) ? in[base + 1] : 0;
    int v2 = (base + 2 < n) ? in[base + 2] : 0;
    int v3 = (base + 3 < n) ? in[base + 3] : 0;
    int s = v0 + v1 + v2 + v3;
    sh[tid] = s;
    __syncthreads();
    for (int off = 1; off < 256; off <<= 1) {
        int t = (tid >= off) ? sh[tid - off] : 0;
        __syncthreads();
        if (tid >= off) sh[tid] += t;
        __syncthreads();
    }
    int excl = sh[tid] - s;
    if (tid == 255) bsums[blockIdx.x] = sh[255];
    if (base + 0 < n) out[base + 0] = excl; excl += v0;
    if (base + 1 < n) out[base + 1] = excl; excl += v1;
    if (base + 2 < n) out[base + 2] = excl; excl += v2;
    if (base + 3 < n) out[base + 3] = excl;
}

__global__ void k_scan_sums(int* bsums, int nb) {  // nb <= 256, single block
    __shared__ int sh[256];
    int tid = threadIdx.x;
    int v = (tid < nb) ? bsums[tid] : 0;
    sh[tid] = v;
    __syncthreads();
    for (int off = 1; off < 256; off <<= 1) {
        int t = (tid >= off) ? sh[tid - off] : 0;
        __syncthreads();
        if (tid >= off) sh[tid] += t;
        __syncthreads();
    }
    if (tid < nb) bsums[tid] = sh[tid] - v;  // exclusive
}

__global__ void k_scan_add(int* out, const int* __restrict__ bsums, int n) {
    int base = blockIdx.x * 1024 + threadIdx.x * 4;
    int add = bsums[blockIdx.x];
#pragma unroll
    for (int j = 0; j < 4; ++j)
        if (base + j < n) out[base + j] += add;
}

__global__ void k_scatter(const int* __restrict__ rows, const int* __restrict__ cols,
                          const float* __restrict__ vals, int* __restrict__ cursor,
                          int* __restrict__ ocol, float* __restrict__ oval, int nE, int maxRow) {
    int e = blockIdx.x * 256 + threadIdx.x;
    if (e >= nE) return;
    int r = rows[e];
    if (r >= maxRow) return;
    int p = atomicAdd(&cursor[r], 1);
    ocol[p] = cols[e];
    oval[p] = vals[e];
}

// ---------------- SpMM (gather form, bf16 output) ----------------
// one wave per row, lane = dim
template <int CONCAT, typename TIN>
__global__ void k_spmm(const int* __restrict__ rp, const int* __restrict__ cnt,
                       const int* __restrict__ ccol, const float* __restrict__ cval,
                       const TIN* __restrict__ x0, const TIN* __restrict__ x1, int split,
                       __hip_bfloat16* __restrict__ out, int nrows) {
    int r = blockIdx.x * 4 + (threadIdx.x >> 6);
    if (r >= nrows) return;
    int lane = threadIdx.x & 63;
    int s = rp[r], n = cnt[r];
    float acc = 0.f;
    for (int i = 0; i < n; ++i) {
        int c = ccol[s + i];
        float v = cval[s + i];
        const TIN* src;
        if (CONCAT)
            src = (c < split) ? (x0 + (size_t)c * 64) : (x1 + (size_t)(c - split) * 64);
        else
            src = x0 + (size_t)c * 64;
        acc += v * ldf(&src[lane]);
    }
    out[(size_t)r * 64 + lane] = __float2bfloat16(acc);
}

// ---------------- gi spmm: edge-parallel atomic (rows < G only) ----------------
__global__ void k_gi_atomic(const int* __restrict__ rows, const int* __restrict__ cols,
                            const float* __restrict__ vals, const float* __restrict__ ge,
                            const float* __restrict__ ie, float* __restrict__ out, int nE) {
    int e = blockIdx.x * 4 + (threadIdx.x >> 6);
    if (e >= nE) return;
    int r = rows[e];
    if (r >= G_N) return;
    int lane = threadIdx.x & 63;
    int c = cols[e];
    float v = vals[e];
    const float* src = (c < G_N) ? (ge + (size_t)c * 64) : (ie + (size_t)(c - G_N) * 64);
    atomicAdd(&out[(size_t)r * 64 + lane], v * src[lane]);
}

// ---------------- accumulation helpers ----------------

__global__ void k_add_grp(float* __restrict__ dst, const __hip_bfloat16* __restrict__ src, int n) {
    int i = blockIdx.x * 256 + threadIdx.x;
    if (i < n) dst[i] += __bfloat162float(src[i]);
}

__global__ void k_init_user_acc(const int* __restrict__ ui, const float* __restrict__ ue,
                                float* __restrict__ ua) {
    int idx = blockIdx.x * 256 + threadIdx.x;
    if (idx >= B_N * 64) return;
    int b = idx >> 6, d = idx & 63;
    ua[idx] = ue[(size_t)ui[b] * 64 + d];
}

__global__ void k_acc_user(const int* __restrict__ ui, const __hip_bfloat16* __restrict__ cur,
                           float* __restrict__ ua) {
    int idx = blockIdx.x * 256 + threadIdx.x;
    if (idx >= B_N * 64) return;
    int b = idx >> 6, d = idx & 63;
    ua[idx] += __bfloat162float(cur[(size_t)ui[b] * 64 + d]);
}

// ---------------- gg = gg_graph @ group_emb ----------------
__global__ __launch_bounds__(256) void gg_gemm(const float* __restrict__ A,
                                               const float* __restrict__ B,
                                               float* __restrict__ out) {
    const int lane = threadIdx.x & 63;
    const int w = threadIdx.x >> 6;
    const int r0 = blockIdx.x * 20 + w * 5;
    float acc[5] = {0.f, 0.f, 0.f, 0.f, 0.f};
    float breg[64];
    int kb = 0;
    for (; kb + 64 <= GG_K; kb += 64) {
#pragma unroll
        for (int j = 0; j < 64; ++j) breg[j] = B[(size_t)(kb + j) * 64 + lane];
#pragma unroll
        for (int rr = 0; rr < 5; ++rr) {
            const float* arow = A + (size_t)(r0 + rr) * GG_K + kb;
            float t0 = 0.f, t1 = 0.f, t2 = 0.f, t3 = 0.f;
#pragma unroll
            for (int j = 0; j < 64; j += 4) {
                t0 += arow[j + 0] * breg[j + 0];
                t1 += arow[j + 1] * breg[j + 1];
                t2 += arow[j + 2] * breg[j + 2];
                t3 += arow[j + 3] * breg[j + 3];
            }
            acc[rr] += (t0 + t1) + (t2 + t3);
        }
    }
    {  // remainder: 10000 - 156*64 = 16
#pragma unroll
        for (int j = 0; j < 16; ++j) breg[j] = B[(size_t)(kb + j) * 64 + lane];
#pragma unroll
        for (int rr = 0; rr < 5; ++rr) {
            const float* arow = A + (size_t)(r0 + rr) * GG_K + kb;
            float t0 = 0.f, t1 = 0.f;
#pragma unroll
            for (int j = 0; j < 16; j += 2) {
                t0 += arow[j] * breg[j];
                t1 += arow[j + 1] * breg[j + 1];
            }
            acc[rr] += t0 + t1;
        }
    }
#pragma unroll
    for (int rr = 0; rr < 5; ++rr) out[(size_t)(r0 + rr) * 64 + lane] = acc[rr];
}

// ---------------- finalize groups ----------------

__global__ void k_finalize(const float* __restrict__ ga, const float* __restrict__ gi,
                           const float* __restrict__ gg, const float* __restrict__ hw,
                           const float* __restrict__ hb, const float* __restrict__ lw,
                           const float* __restrict__ lb, const float* __restrict__ ow,
                           const float* __restrict__ ob, float* __restrict__ gf) {
    int g = blockIdx.x * 4 + (threadIdx.x >> 6);
    if (g >= G_N) return;
    int lane = threadIdx.x & 63;
    size_t o = (size_t)g * 64 + lane;
    float hgv = ga[o] * 0.25f;  // /(LAYERS+1)
    float giv = gi[o];
    float ggv = gg[o];
    float d1 = hgv * hw[lane], d2 = giv * lw[lane], d3 = ggv * ow[lane];
#pragma unroll
    for (int off = 32; off; off >>= 1) {
        d1 += __shfl_xor(d1, off, 64);
        d2 += __shfl_xor(d2, off, 64);
        d3 += __shfl_xor(d3, off, 64);
    }
    float hc = sigmoidf_(d1 + hb[0]);
    float lc = sigmoidf_(d2 + lb[0]);
    float oc = sigmoidf_(d3 + ob[0]);
    gf[o] = hc * hgv + lc * giv + oc * ggv;
}

// ---------------- gather outputs (FLOAT32 — reference outputs are f32) ----------------

__global__ void k_gather_out(const int* __restrict__ ui, const int* __restrict__ pg,
                             const int* __restrict__ ng, const float* __restrict__ ua,
                             const float* __restrict__ gf, const float* __restrict__ ue,
                             const float* __restrict__ ge, float* __restrict__ out) {
    int idx = blockIdx.x * 256 + threadIdx.x;
    if (idx >= B_N * 64) return;
    int b = idx >> 6, d = idx & 63;
    const int S = B_N * 64;
    int u = ui[b], p = pg[b], q = ng[b];
    out[idx]         = ua[idx] * 0.25f;
    out[S + idx]     = gf[(size_t)p * 64 + d];
    out[2 * S + idx] = gf[(size_t)q * 64 + d];
    out[3 * S + idx] = ue[(size_t)u * 64 + d];
    out[4 * S + idx] = ge[(size_t)p * 64 + d];
    out[5 * S + idx] = ge[(size_t)q * 64 + d];
}

extern "C" void kernel_launch(void* const* d_in, const int* in_sizes, int n_in,
                              void* d_out, int out_size, void* d_ws, size_t ws_size,
                              hipStream_t stream) {
    const int*   ui        = (const int*)d_in[0];
    const int*   pg        = (const int*)d_in[1];
    const int*   ng        = (const int*)d_in[2];
    const int*   hg_rows   = (const int*)d_in[3];
    const int*   hg_cols   = (const int*)d_in[4];
    const float* hg_vals   = (const float*)d_in[5];
    const int*   gi_rows   = (const int*)d_in[6];
    const int*   gi_cols   = (const int*)d_in[7];
    const float* gi_vals   = (const float*)d_in[8];
    const float* gg_graph  = (const float*)d_in[9];
    const float* user_emb  = (const float*)d_in[10];
    const float* item_emb  = (const float*)d_in[11];
    const float* group_emb = (const float*)d_in[12];
    const float* hyper_w   = (const float*)d_in[13];
    const float* hyper_b   = (const float*)d_in[14];
    const float* lgcn_w    = (const float*)d_in[15];
    const float* lgcn_b    = (const float*)d_in[16];
    const float* ovl_w     = (const float*)d_in[17];
    const float* ovl_b     = (const float*)d_in[18];
    const int E_HG = in_sizes[3];
    const int E_GI = in_sizes[6];

    // ---- workspace layout: total ~93.6 MB ----
    char* ws = (char*)d_ws;
    size_t off = 0;
    auto alloc = [&](size_t bytes) -> char* {
        char* p = ws + off;
        off += (bytes + 255) & ~(size_t)255;
        return p;
    };
    int*   cnt_hg  = (int*)alloc((size_t)NHG * 4);
    int*   rp_hg   = (int*)alloc((size_t)NHG * 4);
    int*   cur_hg  = (int*)alloc((size_t)NHG * 4);
    int*   ccol_hg = (int*)alloc((size_t)E_HG * 4);
    float* cval_hg = (float*)alloc((size_t)E_HG * 4);
    int*   bsums   = (int*)alloc(256 * 4);
    __hip_bfloat16* curA = (__hip_bfloat16*)alloc((size_t)NHG * 64 * 2);
    __hip_bfloat16* curB = (__hip_bfloat16*)alloc((size_t)NHG * 64 * 2);
    float* grp_acc = (float*)alloc((size_t)G_N * 64 * 4);
    float* gi_out  = (float*)alloc((size_t)G_N * 64 * 4);
    float* gg_out  = (float*)alloc((size_t)G_N * 64 * 4);
    float* grp_fin = (float*)alloc((size_t)G_N * 64 * 4);
    float* usr_acc = (float*)alloc((size_t)B_N * 64 * 4);
    (void)ws_size; (void)n_in; (void)out_size;

    // --- CSR build for hg ---
    hipMemsetAsync(cnt_hg, 0, (size_t)NHG * 4, stream);
    k_hist<<<(E_HG + 255) / 256, 256, 0, stream>>>(hg_rows, cnt_hg, E_HG, NHG);
    int nbh = (NHG + 1023) / 1024;  // 206
    k_scan_partial<<<nbh, 256, 0, stream>>>(cnt_hg, rp_hg, bsums, NHG);
    k_scan_sums<<<1, 256, 0, stream>>>(bsums, nbh);
    k_scan_add<<<nbh, 256, 0, stream>>>(rp_hg, bsums, NHG);
    hipMemcpyAsync(cur_hg, rp_hg, (size_t)NHG * 4, hipMemcpyDeviceToDevice, stream);
    k_scatter<<<(E_HG + 255) / 256, 256, 0, stream>>>(hg_rows, hg_cols, hg_vals, cur_hg,
                                                      ccol_hg, cval_hg, E_HG, NHG);

    // --- init accumulators: acc = hg (layer-0 term) ---
    hipMemcpyAsync(grp_acc, group_emb, (size_t)G_N * 64 * 4, hipMemcpyDeviceToDevice, stream);
    k_init_user_acc<<<(B_N * 64 + 255) / 256, 256, 0, stream>>>(ui, user_emb, usr_acc);

    const int spmm_blk = (NHG + 3) / 4;
    const int gadd_blk = (G_N * 64 + 255) / 256;
    const int uacc_blk = (B_N * 64 + 255) / 256;

    // layer 1 (input = concat(user_emb, group_emb), f32)
    k_spmm<1, float><<<spmm_blk, 256, 0, stream>>>(rp_hg, cnt_hg, ccol_hg, cval_hg,
                                                   user_emb, group_emb, U_N, curA, NHG);
    k_add_grp<<<gadd_blk, 256, 0, stream>>>(grp_acc, curA + (size_t)U_N * 64, G_N * 64);
    k_acc_user<<<uacc_blk, 256, 0, stream>>>(ui, curA, usr_acc);
    // layer 2 (bf16 in, bf16 out)
    k_spmm<0, __hip_bfloat16><<<spmm_blk, 256, 0, stream>>>(rp_hg, cnt_hg, ccol_hg, cval_hg,
                                                            curA, nullptr, 0, curB, NHG);
    k_add_grp<<<gadd_blk, 256, 0, stream>>>(grp_acc, curB + (size_t)U_N * 64, G_N * 64);
    k_acc_user<<<uacc_blk, 256, 0, stream>>>(ui, curB, usr_acc);
    // layer 3
    k_spmm<0, __hip_bfloat16><<<spmm_blk, 256, 0, stream>>>(rp_hg, cnt_hg, ccol_hg, cval_hg,
                                                            curB, nullptr, 0, curA, NHG);
    k_add_grp<<<gadd_blk, 256, 0, stream>>>(grp_acc, curA + (size_t)U_N * 64, G_N * 64);
    k_acc_user<<<uacc_blk, 256, 0, stream>>>(ui, curA, usr_acc);

    // gi spmm (rows < G only), edge-parallel atomics
    hipMemsetAsync(gi_out, 0, (size_t)G_N * 64 * 4, stream);
    k_gi_atomic<<<(E_GI + 3) / 4, 256, 0, stream>>>(gi_rows, gi_cols, gi_vals,
                                                    group_emb, item_emb, gi_out, E_GI);

    // gg dense gemm
    gg_gemm<<<G_N / 20, 256, 0, stream>>>(gg_graph, group_emb, gg_out);

    // finalize + gather
    k_finalize<<<(G_N + 3) / 4, 256, 0, stream>>>(grp_acc, gi_out, gg_out, hyper_w, hyper_b,
                                                  lgcn_w, lgcn_b, ovl_w, ovl_b, grp_fin);
    k_gather_out<<<(B_N * 64 + 255) / 256, 256, 0, stream>>>(ui, pg, ng, usr_acc, grp_fin,
                                                             user_emb, group_emb,
                                                             (float*)d_out);
}

// Round 4
// 1708.582 us; speedup vs baseline: 1.5861x; 1.5861x over previous
//
#include <hip/hip_runtime.h>
#include <hip/hip_bf16.h>

#define U_N 200000
#define I_N 100000
#define G_N 10000
#define B_N 8192
#define NHG (U_N + G_N)   /* 210000 */
#define GG_K 10000
#define GG_KC 313         /* ceil(10000/32) k-chunks */
#define GG_STRIPES 157    /* ceil(10000/64) row stripes */

typedef __attribute__((ext_vector_type(8))) short bf16x8;
typedef __attribute__((ext_vector_type(4))) float f32x4;

static __device__ __forceinline__ float sigmoidf_(float x) {
    return 1.0f / (1.0f + __expf(-x));
}

// f32 -> bf16 bits, round-to-nearest-even
static __device__ __forceinline__ short bfc(float x) {
    unsigned u = __float_as_uint(x);
    unsigned r = (u + 0x7fffu + ((u >> 16) & 1u)) >> 16;
    return (short)r;
}

static __device__ __forceinline__ float ldf(const float* p) { return *p; }
static __device__ __forceinline__ float ldf(const __hip_bfloat16* p) { return __bfloat162float(*p); }

// ---------------- CSR build (hg only) ----------------

__global__ void k_hist(const int* __restrict__ rows, int* __restrict__ cnt, int nE, int maxRow) {
    int e = blockIdx.x * 256 + threadIdx.x;
    if (e >= nE) return;
    int r = rows[e];
    if (r < maxRow) atomicAdd(&cnt[r], 1);
}

__global__ void k_scan_partial(const int* __restrict__ in, int* __restrict__ out,
                               int* __restrict__ bsums, int n) {
    __shared__ int sh[256];
    int tid = threadIdx.x;
    int base = blockIdx.x * 1024 + tid * 4;
    int v0 = (base + 0 < n) ? in[base + 0] : 0;
    int v1 = (base + 1 < n) ? in[base + 1] : 0;
    int v2 = (base + 2 < n) ? in[base + 2] : 0;
    int v3 = (base + 3 < n) ? in[base + 3] : 0;
    int s = v0 + v1 + v2 + v3;
    sh[tid] = s;
    __syncthreads();
    for (int off = 1; off < 256; off <<= 1) {
        int t = (tid >= off) ? sh[tid - off] : 0;
        __syncthreads();
        if (tid >= off) sh[tid] += t;
        __syncthreads();
    }
    int excl = sh[tid] - s;
    if (tid == 255) bsums[blockIdx.x] = sh[255];
    if (base + 0 < n) out[base + 0] = excl; excl += v0;
    if (base + 1 < n) out[base + 1] = excl; excl += v1;
    if (base + 2 < n) out[base + 2] = excl; excl += v2;
    if (base + 3 < n) out[base + 3] = excl;
}

__global__ void k_scan_sums(int* bsums, int nb) {  // nb <= 256, single block
    __shared__ int sh[256];
    int tid = threadIdx.x;
    int v = (tid < nb) ? bsums[tid] : 0;
    sh[tid] = v;
    __syncthreads();
    for (int off = 1; off < 256; off <<= 1) {
        int t = (tid >= off) ? sh[tid - off] : 0;
        __syncthreads();
        if (tid >= off) sh[tid] += t;
        __syncthreads();
    }
    if (tid < nb) bsums[tid] = sh[tid] - v;  // exclusive
}

__global__ void k_scan_add(int* out, const int* __restrict__ bsums, int n) {
    int base = blockIdx.x * 1024 + threadIdx.x * 4;
    int add = bsums[blockIdx.x];
#pragma unroll
    for (int j = 0; j < 4; ++j)
        if (base + j < n) out[base + j] += add;
}

// scatter edges as interleaved (col, val_bits) int2 — one 8B store per edge
__global__ void k_scatter(const int* __restrict__ rows, const int* __restrict__ cols,
                          const float* __restrict__ vals, int* __restrict__ cursor,
                          int2* __restrict__ epair, int nE, int maxRow) {
    int e = blockIdx.x * 256 + threadIdx.x;
    if (e >= nE) return;
    int r = rows[e];
    if (r >= maxRow) return;
    int p = atomicAdd(&cursor[r], 1);
    epair[p] = make_int2(cols[e], __float_as_int(vals[e]));
}

// ---------------- SpMM (gather form, bf16 output) ----------------
// one wave per row, lane = dim
template <int CONCAT, typename TIN>
__global__ void k_spmm(const int* __restrict__ rp, const int* __restrict__ cnt,
                       const int2* __restrict__ epair,
                       const TIN* __restrict__ x0, const TIN* __restrict__ x1, int split,
                       __hip_bfloat16* __restrict__ out, int nrows) {
    int r = blockIdx.x * 4 + (threadIdx.x >> 6);
    if (r >= nrows) return;
    int lane = threadIdx.x & 63;
    int s = rp[r], n = cnt[r];
    float acc = 0.f;
    for (int i = 0; i < n; ++i) {
        int2 e = epair[s + i];
        int c = e.x;
        float v = __int_as_float(e.y);
        const TIN* src;
        if (CONCAT)
            src = (c < split) ? (x0 + (size_t)c * 64) : (x1 + (size_t)(c - split) * 64);
        else
            src = x0 + (size_t)c * 64;
        acc += v * ldf(&src[lane]);
    }
    out[(size_t)r * 64 + lane] = __float2bfloat16(acc);
}

// ---------------- gi spmm: filter + compact + grid-stride atomic ----------------

__global__ void k_gi_filter(const int* __restrict__ rows, const int* __restrict__ cols,
                            const float* __restrict__ vals, int* __restrict__ crow,
                            int* __restrict__ ccol, float* __restrict__ cval,
                            int* __restrict__ ctr, int nE) {
    int e = blockIdx.x * 256 + threadIdx.x;
    if (e >= nE) return;
    int r = rows[e];
    if (r >= G_N) return;
    int p = atomicAdd(ctr, 1);
    crow[p] = r;
    ccol[p] = cols[e];
    cval[p] = vals[e];
}

__global__ void k_gi_atomic(const int* __restrict__ crow, const int* __restrict__ ccol,
                            const float* __restrict__ cval, const float* __restrict__ ge,
                            const float* __restrict__ ie, float* __restrict__ out,
                            const int* __restrict__ ctr) {
    int cnt = *ctr;
    int lane = threadIdx.x & 63;
    int wslot = blockIdx.x * 4 + (threadIdx.x >> 6);
    const int nslots = 4096 * 4;
    for (int e = wslot; e < cnt; e += nslots) {
        int r = crow[e], c = ccol[e];
        float v = cval[e];
        const float* src = (c < G_N) ? (ge + (size_t)c * 64) : (ie + (size_t)(c - G_N) * 64);
        atomicAdd(&out[(size_t)r * 64 + lane], v * src[lane]);
    }
}

// ---------------- accumulation helpers ----------------

__global__ void k_add_grp(float* __restrict__ dst, const __hip_bfloat16* __restrict__ src, int n) {
    int i = blockIdx.x * 256 + threadIdx.x;
    if (i < n) dst[i] += __bfloat162float(src[i]);
}

__global__ void k_init_user_acc(const int* __restrict__ ui, const float* __restrict__ ue,
                                float* __restrict__ ua) {
    int idx = blockIdx.x * 256 + threadIdx.x;
    if (idx >= B_N * 64) return;
    int b = idx >> 6, d = idx & 63;
    ua[idx] = ue[(size_t)ui[b] * 64 + d];
}

__global__ void k_acc_user(const int* __restrict__ ui, const __hip_bfloat16* __restrict__ cur,
                           float* __restrict__ ua) {
    int idx = blockIdx.x * 256 + threadIdx.x;
    if (idx >= B_N * 64) return;
    int b = idx >> 6, d = idx & 63;
    ua[idx] += __bfloat162float(cur[(size_t)ui[b] * 64 + d]);
}

// ---------------- gg = gg_graph @ group_emb via MFMA bf16 ----------------

// Pre-shuffle B (10000x64 f32) into fragment-major bf16:
// Bfrag[(kc*4 + ct)*64 + lane][e] = bf16(B[kc*32 + (lane>>4)*8 + e][ct*16 + (lane&15)])
__global__ void k_bfrag(const float* __restrict__ B, short* __restrict__ Bfrag) {
    int t = blockIdx.x * 256 + threadIdx.x;  // t < 313*4*64 exactly
    int l = t & 63;
    int ct = (t >> 6) & 3;
    int kc = t >> 8;
    int j = ct * 16 + (l & 15);
    int kb = kc * 32 + (l >> 4) * 8;
    short v[8];
#pragma unroll
    for (int e = 0; e < 8; ++e) {
        int k = kb + e;
        float f = (k < GG_K) ? B[(size_t)k * 64 + j] : 0.f;
        v[e] = bfc(f);
    }
    bf16x8 pack;
#pragma unroll
    for (int e = 0; e < 8; ++e) pack[e] = v[e];
    *(bf16x8*)(Bfrag + (size_t)t * 8) = pack;
}

// 628 blocks = 157 row-stripes x 4 K-splits; 256 thr = 4 waves x 16 rows.
__global__ __launch_bounds__(256) void gg_mfma(const float* __restrict__ A,
                                               const short* __restrict__ Bfrag,
                                               float* __restrict__ part) {
    const int stripe = blockIdx.x % GG_STRIPES;
    const int ks = blockIdx.x / GG_STRIPES;  // 0..3
    const int w = threadIdx.x >> 6;
    const int l = threadIdx.x & 63;
    const int r0w = stripe * 64 + w * 16;
    int arow_i = r0w + (l & 15);
    if (arow_i > GG_K - 1) arow_i = GG_K - 1;  // clamp (dup read, store guarded)
    const float* arow = A + (size_t)arow_i * GG_K;
    const int kg8 = (l >> 4) * 8;
    // chunk ranges: [0,79) [79,157) [157,235) [235,313)
    const int c0 = (ks == 0) ? 0 : 79 + 78 * (ks - 1);
    const int c1 = c0 + ((ks == 0) ? 79 : 78);
    f32x4 acc0 = {0.f, 0.f, 0.f, 0.f}, acc1 = acc0, acc2 = acc0, acc3 = acc0;
    for (int kc = c0; kc < c1; ++kc) {
        const int kbase = kc * 32 + kg8;
        bf16x8 af;
        if (kc != GG_KC - 1) {
            const float4 a0 = *(const float4*)(arow + kbase);
            const float4 a1 = *(const float4*)(arow + kbase + 4);
            af[0] = bfc(a0.x); af[1] = bfc(a0.y); af[2] = bfc(a0.z); af[3] = bfc(a0.w);
            af[4] = bfc(a1.x); af[5] = bfc(a1.y); af[6] = bfc(a1.z); af[7] = bfc(a1.w);
        } else {
#pragma unroll
            for (int e = 0; e < 8; ++e) {
                int k = kbase + e;
                af[e] = bfc((k < GG_K) ? arow[k] : 0.f);
            }
        }
        const bf16x8* bp = (const bf16x8*)(Bfrag + (size_t)kc * 4 * 64 * 8);
        bf16x8 b0 = bp[0 * 64 + l];
        bf16x8 b1 = bp[1 * 64 + l];
        bf16x8 b2 = bp[2 * 64 + l];
        bf16x8 b3 = bp[3 * 64 + l];
        acc0 = __builtin_amdgcn_mfma_f32_16x16x32_bf16(af, b0, acc0, 0, 0, 0);
        acc1 = __builtin_amdgcn_mfma_f32_16x16x32_bf16(af, b1, acc1, 0, 0, 0);
        acc2 = __builtin_amdgcn_mfma_f32_16x16x32_bf16(af, b2, acc2, 0, 0, 0);
        acc3 = __builtin_amdgcn_mfma_f32_16x16x32_bf16(af, b3, acc3, 0, 0, 0);
    }
    // D layout: row = (l>>4)*4 + reg, col = ct*16 + (l&15)
    float* po = part + (size_t)ks * GG_K * 64;
    const int orow0 = r0w + (l >> 4) * 4;
    const int ocol = l & 15;
#pragma unroll
    for (int reg = 0; reg < 4; ++reg) {
        int orow = orow0 + reg;
        if (orow < GG_K) {
            float* q = po + (size_t)orow * 64 + ocol;
            q[0]  = acc0[reg];
            q[16] = acc1[reg];
            q[32] = acc2[reg];
            q[48] = acc3[reg];
        }
    }
}

__global__ void k_gg_reduce(const float* __restrict__ part, float* __restrict__ out) {
    int i = blockIdx.x * 256 + threadIdx.x;  // < 640000
    const size_t S = (size_t)GG_K * 64;
    out[i] = part[i] + part[S + i] + part[2 * S + i] + part[3 * S + i];
}

// ---------------- finalize groups ----------------

__global__ void k_finalize(const float* __restrict__ ga, const float* __restrict__ gi,
                           const float* __restrict__ gg, const float* __restrict__ hw,
                           const float* __restrict__ hb, const float* __restrict__ lw,
                           const float* __restrict__ lb, const float* __restrict__ ow,
                           const float* __restrict__ ob, float* __restrict__ gf) {
    int g = blockIdx.x * 4 + (threadIdx.x >> 6);
    if (g >= G_N) return;
    int lane = threadIdx.x & 63;
    size_t o = (size_t)g * 64 + lane;
    float hgv = ga[o] * 0.25f;  // /(LAYERS+1)
    float giv = gi[o];
    float ggv = gg[o];
    float d1 = hgv * hw[lane], d2 = giv * lw[lane], d3 = ggv * ow[lane];
#pragma unroll
    for (int off = 32; off; off >>= 1) {
        d1 += __shfl_xor(d1, off, 64);
        d2 += __shfl_xor(d2, off, 64);
        d3 += __shfl_xor(d3, off, 64);
    }
    float hc = sigmoidf_(d1 + hb[0]);
    float lc = sigmoidf_(d2 + lb[0]);
    float oc = sigmoidf_(d3 + ob[0]);
    gf[o] = hc * hgv + lc * giv + oc * ggv;
}

// ---------------- gather outputs (f32) ----------------

__global__ void k_gather_out(const int* __restrict__ ui, const int* __restrict__ pg,
                             const int* __restrict__ ng, const float* __restrict__ ua,
                             const float* __restrict__ gf, const float* __restrict__ ue,
                             const float* __restrict__ ge, float* __restrict__ out) {
    int idx = blockIdx.x * 256 + threadIdx.x;
    if (idx >= B_N * 64) return;
    int b = idx >> 6, d = idx & 63;
    const int S = B_N * 64;
    int u = ui[b], p = pg[b], q = ng[b];
    out[idx]         = ua[idx] * 0.25f;
    out[S + idx]     = gf[(size_t)p * 64 + d];
    out[2 * S + idx] = gf[(size_t)q * 64 + d];
    out[3 * S + idx] = ue[(size_t)u * 64 + d];
    out[4 * S + idx] = ge[(size_t)p * 64 + d];
    out[5 * S + idx] = ge[(size_t)q * 64 + d];
}

extern "C" void kernel_launch(void* const* d_in, const int* in_sizes, int n_in,
                              void* d_out, int out_size, void* d_ws, size_t ws_size,
                              hipStream_t stream) {
    const int*   ui        = (const int*)d_in[0];
    const int*   pg        = (const int*)d_in[1];
    const int*   ng        = (const int*)d_in[2];
    const int*   hg_rows   = (const int*)d_in[3];
    const int*   hg_cols   = (const int*)d_in[4];
    const float* hg_vals   = (const float*)d_in[5];
    const int*   gi_rows   = (const int*)d_in[6];
    const int*   gi_cols   = (const int*)d_in[7];
    const float* gi_vals   = (const float*)d_in[8];
    const float* gg_graph  = (const float*)d_in[9];
    const float* user_emb  = (const float*)d_in[10];
    const float* item_emb  = (const float*)d_in[11];
    const float* group_emb = (const float*)d_in[12];
    const float* hyper_w   = (const float*)d_in[13];
    const float* hyper_b   = (const float*)d_in[14];
    const float* lgcn_w    = (const float*)d_in[15];
    const float* lgcn_b    = (const float*)d_in[16];
    const float* ovl_w     = (const float*)d_in[17];
    const float* ovl_b     = (const float*)d_in[18];
    const int E_HG = in_sizes[3];
    const int E_GI = in_sizes[6];

    // ---- workspace layout (~105 MB) ----
    char* ws = (char*)d_ws;
    size_t off = 0;
    auto alloc = [&](size_t bytes) -> char* {
        char* p = ws + off;
        off += (bytes + 255) & ~(size_t)255;
        return p;
    };
    int*   cnt_hg  = (int*)alloc((size_t)NHG * 4);
    int*   rp_hg   = (int*)alloc((size_t)NHG * 4);
    int*   cur_hg  = (int*)alloc((size_t)NHG * 4);
    int2*  epair   = (int2*)alloc((size_t)E_HG * 8);
    int*   bsums   = (int*)alloc(256 * 4);
    int*   gi_ctr  = (int*)alloc(256);
    __hip_bfloat16* curA = (__hip_bfloat16*)alloc((size_t)NHG * 64 * 2);
    __hip_bfloat16* curB = (__hip_bfloat16*)alloc((size_t)NHG * 64 * 2);
    float* grp_acc = (float*)alloc((size_t)G_N * 64 * 4);
    float* gi_out  = (float*)alloc((size_t)G_N * 64 * 4);
    float* gg_out  = (float*)alloc((size_t)G_N * 64 * 4);
    float* grp_fin = (float*)alloc((size_t)G_N * 64 * 4);
    float* usr_acc = (float*)alloc((size_t)B_N * 64 * 4);
    short* Bfrag   = (short*)alloc((size_t)GG_KC * 4 * 64 * 8 * 2);
    float* gg_part = (float*)alloc((size_t)4 * GG_K * 64 * 4);
    (void)ws_size; (void)n_in; (void)out_size;

    // gi compact scratch reuses curA (alive only before hg layer 1 writes curA)
    int*   gi_crow = (int*)curA;
    int*   gi_ccol = gi_crow + E_GI;
    float* gi_cval = (float*)(gi_ccol + E_GI);

    // --- CSR build for hg ---
    hipMemsetAsync(cnt_hg, 0, (size_t)NHG * 4, stream);
    k_hist<<<(E_HG + 255) / 256, 256, 0, stream>>>(hg_rows, cnt_hg, E_HG, NHG);
    int nbh = (NHG + 1023) / 1024;  // 206
    k_scan_partial<<<nbh, 256, 0, stream>>>(cnt_hg, rp_hg, bsums, NHG);
    k_scan_sums<<<1, 256, 0, stream>>>(bsums, nbh);
    k_scan_add<<<nbh, 256, 0, stream>>>(rp_hg, bsums, NHG);
    hipMemcpyAsync(cur_hg, rp_hg, (size_t)NHG * 4, hipMemcpyDeviceToDevice, stream);
    k_scatter<<<(E_HG + 255) / 256, 256, 0, stream>>>(hg_rows, hg_cols, hg_vals, cur_hg,
                                                      epair, E_HG, NHG);

    // --- gi spmm (before hg layers so curA can serve as compact scratch) ---
    hipMemsetAsync(gi_out, 0, (size_t)G_N * 64 * 4, stream);
    hipMemsetAsync(gi_ctr, 0, 4, stream);
    k_gi_filter<<<(E_GI + 255) / 256, 256, 0, stream>>>(gi_rows, gi_cols, gi_vals,
                                                        gi_crow, gi_ccol, gi_cval,
                                                        gi_ctr, E_GI);
    k_gi_atomic<<<4096, 256, 0, stream>>>(gi_crow, gi_ccol, gi_cval,
                                          group_emb, item_emb, gi_out, gi_ctr);

    // --- gg via MFMA ---
    k_bfrag<<<GG_KC, 256, 0, stream>>>(group_emb, Bfrag);
    gg_mfma<<<GG_STRIPES * 4, 256, 0, stream>>>(gg_graph, Bfrag, gg_part);
    k_gg_reduce<<<(G_N * 64) / 256, 256, 0, stream>>>(gg_part, gg_out);

    // --- init accumulators: acc = hg (layer-0 term) ---
    hipMemcpyAsync(grp_acc, group_emb, (size_t)G_N * 64 * 4, hipMemcpyDeviceToDevice, stream);
    k_init_user_acc<<<(B_N * 64 + 255) / 256, 256, 0, stream>>>(ui, user_emb, usr_acc);

    const int spmm_blk = (NHG + 3) / 4;
    const int gadd_blk = (G_N * 64 + 255) / 256;
    const int uacc_blk = (B_N * 64 + 255) / 256;

    // layer 1 (input = concat(user_emb, group_emb), f32)
    k_spmm<1, float><<<spmm_blk, 256, 0, stream>>>(rp_hg, cnt_hg, epair,
                                                   user_emb, group_emb, U_N, curA, NHG);
    k_add_grp<<<gadd_blk, 256, 0, stream>>>(grp_acc, curA + (size_t)U_N * 64, G_N * 64);
    k_acc_user<<<uacc_blk, 256, 0, stream>>>(ui, curA, usr_acc);
    // layer 2 (bf16 in, bf16 out)
    k_spmm<0, __hip_bfloat16><<<spmm_blk, 256, 0, stream>>>(rp_hg, cnt_hg, epair,
                                                            curA, nullptr, 0, curB, NHG);
    k_add_grp<<<gadd_blk, 256, 0, stream>>>(grp_acc, curB + (size_t)U_N * 64, G_N * 64);
    k_acc_user<<<uacc_blk, 256, 0, stream>>>(ui, curB, usr_acc);
    // layer 3
    k_spmm<0, __hip_bfloat16><<<spmm_blk, 256, 0, stream>>>(rp_hg, cnt_hg, epair,
                                                            curB, nullptr, 0, curA, NHG);
    k_add_grp<<<gadd_blk, 256, 0, stream>>>(grp_acc, curA + (size_t)U_N * 64, G_N * 64);
    k_acc_user<<<uacc_blk, 256, 0, stream>>>(ui, curA, usr_acc);

    // finalize + gather
    k_finalize<<<(G_N + 3) / 4, 256, 0, stream>>>(grp_acc, gi_out, gg_out, hyper_w, hyper_b,
                                                  lgcn_w, lgcn_b, ovl_w, ovl_b, grp_fin);
    k_gather_out<<<(B_N * 64 + 255) / 256, 256, 0, stream>>>(ui, pg, ng, usr_acc, grp_fin,
                                                             user_emb, group_emb,
                                                             (float*)d_out);
}

// Round 5
// 865.867 us; speedup vs baseline: 3.1298x; 1.9733x over previous
//
#include <hip/hip_runtime.h>
#include <hip/hip_bf16.h>

#define U_N 200000
#define I_N 100000
#define G_N 10000
#define B_N 8192
#define NHG (U_N + G_N)   /* 210000 */
#define GG_K 10000
#define GG_KC 313         /* ceil(10000/32) k-chunks */
#define GG_STRIPES 157    /* ceil(10000/64) row stripes */

typedef __attribute__((ext_vector_type(8))) short bf16x8;
typedef __attribute__((ext_vector_type(4))) float f32x4;

static __device__ __forceinline__ float sigmoidf_(float x) {
    return 1.0f / (1.0f + __expf(-x));
}

// f32 -> bf16 bits, round-to-nearest-even
static __device__ __forceinline__ short bfc(float x) {
    unsigned u = __float_as_uint(x);
    unsigned r = (u + 0x7fffu + ((u >> 16) & 1u)) >> 16;
    return (short)r;
}

// ---------------- CSR build (hg only) ----------------

__global__ void k_hist(const int* __restrict__ rows, int* __restrict__ cnt, int nE, int maxRow) {
    int e = blockIdx.x * 256 + threadIdx.x;
    if (e >= nE) return;
    int r = rows[e];
    if (r < maxRow) atomicAdd(&cnt[r], 1);
}

__global__ void k_scan_partial(const int* __restrict__ in, int* __restrict__ out,
                               int* __restrict__ bsums, int n) {
    __shared__ int sh[256];
    int tid = threadIdx.x;
    int base = blockIdx.x * 1024 + tid * 4;
    int v0 = (base + 0 < n) ? in[base + 0] : 0;
    int v1 = (base + 1 < n) ? in[base + 1] : 0;
    int v2 = (base + 2 < n) ? in[base + 2] : 0;
    int v3 = (base + 3 < n) ? in[base + 3] : 0;
    int s = v0 + v1 + v2 + v3;
    sh[tid] = s;
    __syncthreads();
    for (int off = 1; off < 256; off <<= 1) {
        int t = (tid >= off) ? sh[tid - off] : 0;
        __syncthreads();
        if (tid >= off) sh[tid] += t;
        __syncthreads();
    }
    int excl = sh[tid] - s;
    if (tid == 255) bsums[blockIdx.x] = sh[255];
    if (base + 0 < n) out[base + 0] = excl; excl += v0;
    if (base + 1 < n) out[base + 1] = excl; excl += v1;
    if (base + 2 < n) out[base + 2] = excl; excl += v2;
    if (base + 3 < n) out[base + 3] = excl;
}

__global__ void k_scan_sums(int* bsums, int nb) {  // nb <= 256, single block
    __shared__ int sh[256];
    int tid = threadIdx.x;
    int v = (tid < nb) ? bsums[tid] : 0;
    sh[tid] = v;
    __syncthreads();
    for (int off = 1; off < 256; off <<= 1) {
        int t = (tid >= off) ? sh[tid - off] : 0;
        __syncthreads();
        if (tid >= off) sh[tid] += t;
        __syncthreads();
    }
    if (tid < nb) bsums[tid] = sh[tid] - v;  // exclusive
}

__global__ void k_scan_add(int* out, const int* __restrict__ bsums, int n) {
    int base = blockIdx.x * 1024 + threadIdx.x * 4;
    int add = bsums[blockIdx.x];
#pragma unroll
    for (int j = 0; j < 4; ++j)
        if (base + j < n) out[base + j] += add;
}

// scatter edges as interleaved (col, val_bits) int2 — one 8B store per edge
__global__ void k_scatter(const int* __restrict__ rows, const int* __restrict__ cols,
                          const float* __restrict__ vals, int* __restrict__ cursor,
                          int2* __restrict__ epair, int nE, int maxRow) {
    int e = blockIdx.x * 256 + threadIdx.x;
    if (e >= nE) return;
    int r = rows[e];
    if (r >= maxRow) return;
    int p = atomicAdd(&cursor[r], 1);
    epair[p] = make_int2(cols[e], __float_as_int(vals[e]));
}

// ---------------- SpMM (gather form, bf16 in, bf16 out) ----------------
// one wave per row, lane = dim
__global__ void k_spmm(const int* __restrict__ rp, const int* __restrict__ cnt,
                       const int2* __restrict__ epair,
                       const __hip_bfloat16* __restrict__ x,
                       __hip_bfloat16* __restrict__ out, int nrows) {
    int r = blockIdx.x * 4 + (threadIdx.x >> 6);
    if (r >= nrows) return;
    int lane = threadIdx.x & 63;
    int s = rp[r], n = cnt[r];
    float acc = 0.f;
    int i = 0;
    for (; i + 2 <= n; i += 2) {
        int2 e0 = epair[s + i];
        int2 e1 = epair[s + i + 1];
        float x0 = __bfloat162float(x[(size_t)e0.x * 64 + lane]);
        float x1 = __bfloat162float(x[(size_t)e1.x * 64 + lane]);
        acc += __int_as_float(e0.y) * x0;
        acc += __int_as_float(e1.y) * x1;
    }
    if (i < n) {
        int2 e0 = epair[s + i];
        acc += __int_as_float(e0.y) * __bfloat162float(x[(size_t)e0.x * 64 + lane]);
    }
    out[(size_t)r * 64 + lane] = __float2bfloat16(acc);
}

// layer-3 targeted spmm: tasks 0..G_N-1 -> group row U_N+t (+= grp_acc);
// tasks G_N..G_N+B_N-1 -> user row ui[b] (+= usr_acc[b])
__global__ void k_spmm_final(const int* __restrict__ rp, const int* __restrict__ cnt,
                             const int2* __restrict__ epair,
                             const __hip_bfloat16* __restrict__ x,
                             const int* __restrict__ ui,
                             float* __restrict__ grp_acc, float* __restrict__ usr_acc) {
    int t = blockIdx.x * 4 + (threadIdx.x >> 6);
    if (t >= G_N + B_N) return;
    int lane = threadIdx.x & 63;
    int r = (t < G_N) ? (U_N + t) : ui[t - G_N];
    int s = rp[r], n = cnt[r];
    float acc = 0.f;
    int i = 0;
    for (; i + 2 <= n; i += 2) {
        int2 e0 = epair[s + i];
        int2 e1 = epair[s + i + 1];
        float x0 = __bfloat162float(x[(size_t)e0.x * 64 + lane]);
        float x1 = __bfloat162float(x[(size_t)e1.x * 64 + lane]);
        acc += __int_as_float(e0.y) * x0;
        acc += __int_as_float(e1.y) * x1;
    }
    if (i < n) {
        int2 e0 = epair[s + i];
        acc += __int_as_float(e0.y) * __bfloat162float(x[(size_t)e0.x * 64 + lane]);
    }
    if (t < G_N)
        grp_acc[(size_t)t * 64 + lane] += acc;
    else
        usr_acc[(size_t)(t - G_N) * 64 + lane] += acc;
}

// ---------------- gi spmm: ballot-batched edge-parallel atomic ----------------
__global__ void k_gi_spmm(const int* __restrict__ rows, const int* __restrict__ cols,
                          const float* __restrict__ vals, const float* __restrict__ ge,
                          const float* __restrict__ ie, float* __restrict__ out, int nE) {
    int lane = threadIdx.x & 63;
    long wslot = blockIdx.x * 4 + (threadIdx.x >> 6);
    const long nslots = 2048 * 4;
    for (long base = wslot * 64; base < nE; base += nslots * 64) {
        long e = base + lane;
        int r = (e < nE) ? rows[e] : 0x7fffffff;
        bool ok = (r < G_N);
        int c = 0;
        float v = 0.f;
        if (ok) { c = cols[e]; v = vals[e]; }
        unsigned long long mask = __ballot(ok);
        while (mask) {
            int srcl = __ffsll(mask) - 1;
            mask &= mask - 1;
            int rr = __shfl(r, srcl, 64);
            int cc = __shfl(c, srcl, 64);
            float vv = __shfl(v, srcl, 64);
            const float* sp = (cc < G_N) ? (ge + (size_t)cc * 64) : (ie + (size_t)(cc - G_N) * 64);
            atomicAdd(&out[(size_t)rr * 64 + lane], vv * sp[lane]);
        }
    }
}

// ---------------- accumulation helpers ----------------

__global__ void k_add_grp(float* __restrict__ dst, const __hip_bfloat16* __restrict__ src, int n) {
    int i = blockIdx.x * 256 + threadIdx.x;
    if (i < n) dst[i] += __bfloat162float(src[i]);
}

__global__ void k_init_user_acc(const int* __restrict__ ui, const float* __restrict__ ue,
                                float* __restrict__ ua) {
    int idx = blockIdx.x * 256 + threadIdx.x;
    if (idx >= B_N * 64) return;
    int b = idx >> 6, d = idx & 63;
    ua[idx] = ue[(size_t)ui[b] * 64 + d];
}

__global__ void k_acc_user(const int* __restrict__ ui, const __hip_bfloat16* __restrict__ cur,
                           float* __restrict__ ua) {
    int idx = blockIdx.x * 256 + threadIdx.x;
    if (idx >= B_N * 64) return;
    int b = idx >> 6, d = idx & 63;
    ua[idx] += __bfloat162float(cur[(size_t)ui[b] * 64 + d]);
}

// concat(user_emb, group_emb) f32 -> bf16 table (vectorized 4/thread)
__global__ void k_cvt_cat(const float4* __restrict__ ue4, const float4* __restrict__ ge4,
                          ushort4* __restrict__ out4) {
    int i = blockIdx.x * 256 + threadIdx.x;
    if (i >= NHG * 16) return;
    float4 f = (i < U_N * 16) ? ue4[i] : ge4[i - U_N * 16];
    ushort4 o;
    o.x = (unsigned short)bfc(f.x);
    o.y = (unsigned short)bfc(f.y);
    o.z = (unsigned short)bfc(f.z);
    o.w = (unsigned short)bfc(f.w);
    out4[i] = o;
}

// ---------------- gg = gg_graph @ group_emb via MFMA bf16 ----------------

// Bfrag[(kc*4 + ct)*64 + lane][e] = bf16(B[kc*32 + (lane>>4)*8 + e][ct*16 + (lane&15)])
__global__ void k_bfrag(const float* __restrict__ B, short* __restrict__ Bfrag) {
    int t = blockIdx.x * 256 + threadIdx.x;  // t < 313*4*64 exactly
    int l = t & 63;
    int ct = (t >> 6) & 3;
    int kc = t >> 8;
    int j = ct * 16 + (l & 15);
    int kb = kc * 32 + (l >> 4) * 8;
    short v[8];
#pragma unroll
    for (int e = 0; e < 8; ++e) {
        int k = kb + e;
        float f = (k < GG_K) ? B[(size_t)k * 64 + j] : 0.f;
        v[e] = bfc(f);
    }
    bf16x8 pack;
#pragma unroll
    for (int e = 0; e < 8; ++e) pack[e] = v[e];
    *(bf16x8*)(Bfrag + (size_t)t * 8) = pack;
}

// 628 blocks = 157 row-stripes x 4 K-splits; 256 thr = 4 waves x 16 rows.
__global__ __launch_bounds__(256) void gg_mfma(const float* __restrict__ A,
                                               const short* __restrict__ Bfrag,
                                               float* __restrict__ part) {
    const int stripe = blockIdx.x % GG_STRIPES;
    const int ks = blockIdx.x / GG_STRIPES;  // 0..3
    const int w = threadIdx.x >> 6;
    const int l = threadIdx.x & 63;
    const int r0w = stripe * 64 + w * 16;
    int arow_i = r0w + (l & 15);
    if (arow_i > GG_K - 1) arow_i = GG_K - 1;  // clamp (dup read, store guarded)
    const float* arow = A + (size_t)arow_i * GG_K;
    const int kg8 = (l >> 4) * 8;
    const int c0 = (ks == 0) ? 0 : 79 + 78 * (ks - 1);
    const int c1 = c0 + ((ks == 0) ? 79 : 78);
    f32x4 acc0 = {0.f, 0.f, 0.f, 0.f}, acc1 = acc0, acc2 = acc0, acc3 = acc0;
    for (int kc = c0; kc < c1; ++kc) {
        const int kbase = kc * 32 + kg8;
        bf16x8 af;
        if (kc != GG_KC - 1) {
            const float4 a0 = *(const float4*)(arow + kbase);
            const float4 a1 = *(const float4*)(arow + kbase + 4);
            af[0] = bfc(a0.x); af[1] = bfc(a0.y); af[2] = bfc(a0.z); af[3] = bfc(a0.w);
            af[4] = bfc(a1.x); af[5] = bfc(a1.y); af[6] = bfc(a1.z); af[7] = bfc(a1.w);
        } else {
#pragma unroll
            for (int e = 0; e < 8; ++e) {
                int k = kbase + e;
                af[e] = bfc((k < GG_K) ? arow[k] : 0.f);
            }
        }
        const bf16x8* bp = (const bf16x8*)(Bfrag + (size_t)kc * 4 * 64 * 8);
        bf16x8 b0 = bp[0 * 64 + l];
        bf16x8 b1 = bp[1 * 64 + l];
        bf16x8 b2 = bp[2 * 64 + l];
        bf16x8 b3 = bp[3 * 64 + l];
        acc0 = __builtin_amdgcn_mfma_f32_16x16x32_bf16(af, b0, acc0, 0, 0, 0);
        acc1 = __builtin_amdgcn_mfma_f32_16x16x32_bf16(af, b1, acc1, 0, 0, 0);
        acc2 = __builtin_amdgcn_mfma_f32_16x16x32_bf16(af, b2, acc2, 0, 0, 0);
        acc3 = __builtin_amdgcn_mfma_f32_16x16x32_bf16(af, b3, acc3, 0, 0, 0);
    }
    // D layout: row = (l>>4)*4 + reg, col = ct*16 + (l&15)
    float* po = part + (size_t)ks * GG_K * 64;
    const int orow0 = r0w + (l >> 4) * 4;
    const int ocol = l & 15;
#pragma unroll
    for (int reg = 0; reg < 4; ++reg) {
        int orow = orow0 + reg;
        if (orow < GG_K) {
            float* q = po + (size_t)orow * 64 + ocol;
            q[0]  = acc0[reg];
            q[16] = acc1[reg];
            q[32] = acc2[reg];
            q[48] = acc3[reg];
        }
    }
}

__global__ void k_gg_reduce(const float* __restrict__ part, float* __restrict__ out) {
    int i = blockIdx.x * 256 + threadIdx.x;  // < 640000
    const size_t S = (size_t)GG_K * 64;
    out[i] = part[i] + part[S + i] + part[2 * S + i] + part[3 * S + i];
}

// ---------------- finalize groups ----------------

__global__ void k_finalize(const float* __restrict__ ga, const float* __restrict__ gi,
                           const float* __restrict__ gg, const float* __restrict__ hw,
                           const float* __restrict__ hb, const float* __restrict__ lw,
                           const float* __restrict__ lb, const float* __restrict__ ow,
                           const float* __restrict__ ob, float* __restrict__ gf) {
    int g = blockIdx.x * 4 + (threadIdx.x >> 6);
    if (g >= G_N) return;
    int lane = threadIdx.x & 63;
    size_t o = (size_t)g * 64 + lane;
    float hgv = ga[o] * 0.25f;  // /(LAYERS+1)
    float giv = gi[o];
    float ggv = gg[o];
    float d1 = hgv * hw[lane], d2 = giv * lw[lane], d3 = ggv * ow[lane];
#pragma unroll
    for (int off = 32; off; off >>= 1) {
        d1 += __shfl_xor(d1, off, 64);
        d2 += __shfl_xor(d2, off, 64);
        d3 += __shfl_xor(d3, off, 64);
    }
    float hc = sigmoidf_(d1 + hb[0]);
    float lc = sigmoidf_(d2 + lb[0]);
    float oc = sigmoidf_(d3 + ob[0]);
    gf[o] = hc * hgv + lc * giv + oc * ggv;
}

// ---------------- gather outputs (f32) ----------------

__global__ void k_gather_out(const int* __restrict__ ui, const int* __restrict__ pg,
                             const int* __restrict__ ng, const float* __restrict__ ua,
                             const float* __restrict__ gf, const float* __restrict__ ue,
                             const float* __restrict__ ge, float* __restrict__ out) {
    int idx = blockIdx.x * 256 + threadIdx.x;
    if (idx >= B_N * 64) return;
    int b = idx >> 6, d = idx & 63;
    const int S = B_N * 64;
    int u = ui[b], p = pg[b], q = ng[b];
    out[idx]         = ua[idx] * 0.25f;
    out[S + idx]     = gf[(size_t)p * 64 + d];
    out[2 * S + idx] = gf[(size_t)q * 64 + d];
    out[3 * S + idx] = ue[(size_t)u * 64 + d];
    out[4 * S + idx] = ge[(size_t)p * 64 + d];
    out[5 * S + idx] = ge[(size_t)q * 64 + d];
}

extern "C" void kernel_launch(void* const* d_in, const int* in_sizes, int n_in,
                              void* d_out, int out_size, void* d_ws, size_t ws_size,
                              hipStream_t stream) {
    const int*   ui        = (const int*)d_in[0];
    const int*   pg        = (const int*)d_in[1];
    const int*   ng        = (const int*)d_in[2];
    const int*   hg_rows   = (const int*)d_in[3];
    const int*   hg_cols   = (const int*)d_in[4];
    const float* hg_vals   = (const float*)d_in[5];
    const int*   gi_rows   = (const int*)d_in[6];
    const int*   gi_cols   = (const int*)d_in[7];
    const float* gi_vals   = (const float*)d_in[8];
    const float* gg_graph  = (const float*)d_in[9];
    const float* user_emb  = (const float*)d_in[10];
    const float* item_emb  = (const float*)d_in[11];
    const float* group_emb = (const float*)d_in[12];
    const float* hyper_w   = (const float*)d_in[13];
    const float* hyper_b   = (const float*)d_in[14];
    const float* lgcn_w    = (const float*)d_in[15];
    const float* lgcn_b    = (const float*)d_in[16];
    const float* ovl_w     = (const float*)d_in[17];
    const float* ovl_b     = (const float*)d_in[18];
    const int E_HG = in_sizes[3];
    const int E_GI = in_sizes[6];

    // ---- workspace layout (~105 MB) ----
    char* ws = (char*)d_ws;
    size_t off = 0;
    auto alloc = [&](size_t bytes) -> char* {
        char* p = ws + off;
        off += (bytes + 255) & ~(size_t)255;
        return p;
    };
    int*   cnt_hg  = (int*)alloc((size_t)NHG * 4);
    int*   rp_hg   = (int*)alloc((size_t)NHG * 4);
    int*   cur_hg  = (int*)alloc((size_t)NHG * 4);
    int2*  epair   = (int2*)alloc((size_t)E_HG * 8);
    int*   bsums   = (int*)alloc(256 * 4);
    __hip_bfloat16* curA = (__hip_bfloat16*)alloc((size_t)NHG * 64 * 2);
    __hip_bfloat16* curB = (__hip_bfloat16*)alloc((size_t)NHG * 64 * 2);
    float* grp_acc = (float*)alloc((size_t)G_N * 64 * 4);
    float* gi_out  = (float*)alloc((size_t)G_N * 64 * 4);
    float* gg_out  = (float*)alloc((size_t)G_N * 64 * 4);
    float* grp_fin = (float*)alloc((size_t)G_N * 64 * 4);
    float* usr_acc = (float*)alloc((size_t)B_N * 64 * 4);
    short* Bfrag   = (short*)alloc((size_t)GG_KC * 4 * 64 * 8 * 2);
    float* gg_part = (float*)alloc((size_t)4 * GG_K * 64 * 4);
    (void)ws_size; (void)n_in; (void)out_size;

    // --- CSR build for hg ---
    hipMemsetAsync(cnt_hg, 0, (size_t)NHG * 4, stream);
    k_hist<<<(E_HG + 255) / 256, 256, 0, stream>>>(hg_rows, cnt_hg, E_HG, NHG);
    int nbh = (NHG + 1023) / 1024;  // 206
    k_scan_partial<<<nbh, 256, 0, stream>>>(cnt_hg, rp_hg, bsums, NHG);
    k_scan_sums<<<1, 256, 0, stream>>>(bsums, nbh);
    k_scan_add<<<nbh, 256, 0, stream>>>(rp_hg, bsums, NHG);
    hipMemcpyAsync(cur_hg, rp_hg, (size_t)NHG * 4, hipMemcpyDeviceToDevice, stream);
    k_scatter<<<(E_HG + 255) / 256, 256, 0, stream>>>(hg_rows, hg_cols, hg_vals, cur_hg,
                                                      epair, E_HG, NHG);

    // --- gi spmm: ballot-batched, no compaction ---
    hipMemsetAsync(gi_out, 0, (size_t)G_N * 64 * 4, stream);
    k_gi_spmm<<<2048, 256, 0, stream>>>(gi_rows, gi_cols, gi_vals,
                                        group_emb, item_emb, gi_out, E_GI);

    // --- gg via MFMA ---
    k_bfrag<<<GG_KC, 256, 0, stream>>>(group_emb, Bfrag);
    gg_mfma<<<GG_STRIPES * 4, 256, 0, stream>>>(gg_graph, Bfrag, gg_part);
    k_gg_reduce<<<(G_N * 64) / 256, 256, 0, stream>>>(gg_part, gg_out);

    // --- init accumulators: acc = hg (layer-0 term) ---
    hipMemcpyAsync(grp_acc, group_emb, (size_t)G_N * 64 * 4, hipMemcpyDeviceToDevice, stream);
    k_init_user_acc<<<(B_N * 64 + 255) / 256, 256, 0, stream>>>(ui, user_emb, usr_acc);

    // --- bf16 base table into curB (free until layer-2 output) ---
    k_cvt_cat<<<(NHG * 16 + 255) / 256, 256, 0, stream>>>(
        (const float4*)user_emb, (const float4*)group_emb, (ushort4*)curB);

    const int spmm_blk = (NHG + 3) / 4;
    const int gadd_blk = (G_N * 64 + 255) / 256;
    const int uacc_blk = (B_N * 64 + 255) / 256;

    // layer 1: curB (base emb bf16) -> curA
    k_spmm<<<spmm_blk, 256, 0, stream>>>(rp_hg, cnt_hg, epair, curB, curA, NHG);
    k_add_grp<<<gadd_blk, 256, 0, stream>>>(grp_acc, curA + (size_t)U_N * 64, G_N * 64);
    k_acc_user<<<uacc_blk, 256, 0, stream>>>(ui, curA, usr_acc);
    // layer 2: curA -> curB (base emb no longer needed)
    k_spmm<<<spmm_blk, 256, 0, stream>>>(rp_hg, cnt_hg, epair, curA, curB, NHG);
    k_add_grp<<<gadd_blk, 256, 0, stream>>>(grp_acc, curB + (size_t)U_N * 64, G_N * 64);
    k_acc_user<<<uacc_blk, 256, 0, stream>>>(ui, curB, usr_acc);
    // layer 3: targeted (group rows + ui rows only), accumulate in place
    k_spmm_final<<<(G_N + B_N + 3) / 4, 256, 0, stream>>>(rp_hg, cnt_hg, epair, curB, ui,
                                                          grp_acc, usr_acc);

    // finalize + gather
    k_finalize<<<(G_N + 3) / 4, 256, 0, stream>>>(grp_acc, gi_out, gg_out, hyper_w, hyper_b,
                                                  lgcn_w, lgcn_b, ovl_w, ovl_b, grp_fin);
    k_gather_out<<<(B_N * 64 + 255) / 256, 256, 0, stream>>>(ui, pg, ng, usr_acc, grp_fin,
                                                             user_emb, group_emb,
                                                             (float*)d_out);
}